// Round 10
// baseline (130.623 us; speedup 1.0000x reference)
//
#include <hip/hip_runtime.h>

// LightweightConv1d: x (T,B,C) f32, weight (H,1,K) f32 (softmax over K), bias (C) f32
// out[t,b,c] = bias[c] + sum_k softmax(w[h])[k] * x[t-P+k, b, c],  h = c / (C/H)
//
// Direct-load float4 streaming. Series lesson: we are outstanding-bytes-bound
// (Little's law: ~1 load in flight/wave x 256B / ~450cyc => ~4.4 TB/s = R6).
// Fix the bytes-per-load-slot (256B -> 1024B float4), NOT the loads-in-flight
// (R7 fences failed) and NOT via LDS (R9 serialization). Keep un-remat state at
// R6's proven-safe 32 VGPRs: 8 float4 accumulators (4 channels x 8 t per thread).
// Wave = ONE head (8 float4-cols x 8 t-groups) -> weights in SGPR.
#define T_DIM 2048
#define B_DIM 32
#define C_DIM 512
#define H_DIM 16
#define K_DIM 31
#define P_PAD 15
#define TP 8                       // t-outputs per thread
#define JNN (TP + K_DIM - 1)       // 38 streamed float4 inputs per thread
#define NC4 (B_DIM * C_DIM / 4)    // 4096 float4 between consecutive t

__global__ __launch_bounds__(256, 4)
void lwconv_kernel(const float4* __restrict__ x4, const float* __restrict__ weight,
                   const float* __restrict__ bias, float4* __restrict__ out4)
{
    const int wid  = __builtin_amdgcn_readfirstlane((int)(threadIdx.x >> 6));
    const int lane = threadIdx.x & 63;
    const int gw   = blockIdx.x * 4 + wid;        // global wave id (scalar)
    const int h    = gw & (H_DIM - 1);            // head (wave-uniform)
    const int b    = (gw >> 4) & (B_DIM - 1);     // batch (uniform)
    const int tseg = gw >> 9;                     // t-segment 0..31 (uniform)
    const int c4   = lane & 7;                    // float4-col within head (8 = 32 ch)
    const int tq   = lane >> 3;                   // t-group 0..7

    // per-lane softmax of the head's 31 weights (uniform inputs), then -> SGPR
    float w[K_DIM];
    float m = -3.4e38f;
    #pragma unroll
    for (int k = 0; k < K_DIM; ++k) { w[k] = weight[h * K_DIM + k]; m = fmaxf(m, w[k]); }
    float s = 0.f;
    #pragma unroll
    for (int k = 0; k < K_DIM; ++k) { w[k] = __expf(w[k] - m); s += w[k]; }
    const float inv = 1.f / s;
    unsigned int ws[K_DIM];
    #pragma unroll
    for (int k = 0; k < K_DIM; ++k)
        ws[k] = __builtin_amdgcn_readfirstlane(__float_as_uint(w[k] * inv));

    const int col4 = b * (C_DIM / 4) + (h << 3) + c4;   // float4 index in a t-row
    const float4 bv = ((const float4*)bias)[(h << 3) + c4];
    const int tb = tseg * 64 + (tq << 3);         // first output t of this thread
    const float4* xp = x4 + col4;
    float4*       op = out4 + col4;

    float4 acc[TP];
    #pragma unroll
    for (int i = 0; i < TP; ++i) acc[i] = bv;

    // Stream 38 float4 rows; input j feeds accs [j-30, j] clipped to [0,7].
    if (tseg == 0 || tseg == 31) {
        #pragma unroll
        for (int j = 0; j < JNN; ++j) {
            const int t = tb - P_PAD + j;
            int tc = t < 0 ? 0 : (t >= T_DIM ? T_DIM - 1 : t);
            float4 v = xp[(size_t)tc * NC4];
            if (t < 0 || t >= T_DIM) { v.x = 0.f; v.y = 0.f; v.z = 0.f; v.w = 0.f; }
            const int ilo = (j - (K_DIM - 1)) > 0 ? (j - (K_DIM - 1)) : 0;
            const int ihi = j < (TP - 1) ? j : (TP - 1);
            #pragma unroll
            for (int i = ilo; i <= ihi; ++i) {
                const float wk = __uint_as_float(ws[j - i]);
                acc[i].x = fmaf(wk, v.x, acc[i].x);
                acc[i].y = fmaf(wk, v.y, acc[i].y);
                acc[i].z = fmaf(wk, v.z, acc[i].z);
                acc[i].w = fmaf(wk, v.w, acc[i].w);
            }
        }
    } else {
        #pragma unroll
        for (int j = 0; j < JNN; ++j) {
            float4 v = xp[(size_t)(tb - P_PAD + j) * NC4];
            const int ilo = (j - (K_DIM - 1)) > 0 ? (j - (K_DIM - 1)) : 0;
            const int ihi = j < (TP - 1) ? j : (TP - 1);
            #pragma unroll
            for (int i = ilo; i <= ihi; ++i) {
                const float wk = __uint_as_float(ws[j - i]);
                acc[i].x = fmaf(wk, v.x, acc[i].x);
                acc[i].y = fmaf(wk, v.y, acc[i].y);
                acc[i].z = fmaf(wk, v.z, acc[i].z);
                acc[i].w = fmaf(wk, v.w, acc[i].w);
            }
        }
    }

    #pragma unroll
    for (int i = 0; i < TP; ++i)
        op[(size_t)(tb + i) * NC4] = acc[i];
}

extern "C" void kernel_launch(void* const* d_in, const int* in_sizes, int n_in,
                              void* d_out, int out_size, void* d_ws, size_t ws_size,
                              hipStream_t stream) {
    const float4* x4    = (const float4*)d_in[0];
    const float* weight = (const float*)d_in[1];
    const float* bias   = (const float*)d_in[2];
    float4* out4 = (float4*)d_out;
    // waves = H(16) * B(32) * t-segments(32) = 16384 -> 4096 blocks of 4 waves
    dim3 grid(H_DIM * B_DIM * (T_DIM / 64) / 4);
    dim3 block(256);
    lwconv_kernel<<<grid, block, 0, stream>>>(x4, weight, bias, out4);
}

// Round 11
// 72.872 us; speedup vs baseline: 1.7925x; 1.7925x over previous
//
#include <hip/hip_runtime.h>

// LightweightConv1d: x (T,B,C) f32, weight (H,1,K) f32 (softmax over K), bias (C) f32
// out[t,b,c] = bias[c] + sum_k softmax(w[h])[k] * x[t-P+k, b, c],  h = c / (C/H)
//
// float2-streaming with SCALAR accumulator arrays + 2-deep load pipeline.
// Series post-mortems: float4/float2 STRUCT accumulators get dumped to scratch
// wholesale (R8/R10: scratch bytes == sizeof(acc) exactly); scalar acc arrays
// SROA cleanly (R6: VGPR=36, no spill). Loads, not accs, carry the width:
// ext_vector float2 loads (512B/wave/slot, 2x R6) + explicit 2-deep pipeline
// (load j+1 issued before j's FMAs; +2 VGPR) -> 2-4x outstanding bytes vs R6.
#define T_DIM 2048
#define B_DIM 32
#define C_DIM 512
#define H_DIM 16
#define K_DIM 31
#define P_PAD 15
#define TP 16                      // t-outputs per thread (x 2 channels)
#define JN (TP + K_DIM - 1)        // 46 streamed float2 rows per thread
#define NC2 (B_DIM * C_DIM / 2)    // 8192 float2 between consecutive t

typedef float f32x2 __attribute__((ext_vector_type(2)));

__global__ __launch_bounds__(256, 4)
void lwconv_kernel(const f32x2* __restrict__ x2, const float* __restrict__ weight,
                   const float* __restrict__ bias, f32x2* __restrict__ out2)
{
    const int wid  = __builtin_amdgcn_readfirstlane((int)(threadIdx.x >> 6));
    const int lane = threadIdx.x & 63;
    const int gw   = blockIdx.x * 4 + wid;        // global wave id (scalar)
    const int h    = gw & (H_DIM - 1);            // head (wave-uniform)
    const int bq   = (gw >> 4) & 7;               // batch quad (uniform)
    const int tseg = gw >> 7;                     // t-segment 0..127 (uniform)
    const int c2   = lane & 15;                   // float2-col within head (16 = 32 ch)
    const int bl   = lane >> 4;                   // batch within quad
    const int b    = (bq << 2) | bl;

    // per-lane softmax of the head's 31 weights (uniform inputs), then -> SGPR
    float w[K_DIM];
    float m = -3.4e38f;
    #pragma unroll
    for (int k = 0; k < K_DIM; ++k) { w[k] = weight[h * K_DIM + k]; m = fmaxf(m, w[k]); }
    float s = 0.f;
    #pragma unroll
    for (int k = 0; k < K_DIM; ++k) { w[k] = __expf(w[k] - m); s += w[k]; }
    const float inv = 1.f / s;
    unsigned int ws[K_DIM];
    #pragma unroll
    for (int k = 0; k < K_DIM; ++k)
        ws[k] = __builtin_amdgcn_readfirstlane(__float_as_uint(w[k] * inv));

    const int col2 = b * (C_DIM / 2) + (h << 4) + c2;   // float2 index in a t-row
    const f32x2 bv = ((const f32x2*)bias)[(h << 4) + c2];
    const int tb = tseg * TP;                     // first output t of this thread
    const f32x2* xp = x2 + col2;
    f32x2*       op = out2 + col2;

    // SCALAR accumulator arrays (SROA-proven layout; 32 VGPRs total)
    float aA[TP], aB[TP];
    #pragma unroll
    for (int i = 0; i < TP; ++i) { aA[i] = bv[0]; aB[i] = bv[1]; }

#define FMAS(J, V)                                                        \
    {                                                                     \
        const int ilo = ((J) - (K_DIM - 1)) > 0 ? ((J) - (K_DIM - 1)) : 0;\
        const int ihi = (J) < (TP - 1) ? (J) : (TP - 1);                  \
        _Pragma("unroll")                                                 \
        for (int i = ilo; i <= ihi; ++i) {                                \
            const float wk = __uint_as_float(ws[(J) - i]);                \
            aA[i] = fmaf(wk, (V)[0], aA[i]);                              \
            aB[i] = fmaf(wk, (V)[1], aB[i]);                              \
        }                                                                 \
    }

    if (tseg == 0 || tseg == (T_DIM / TP) - 1) {
        // boundary: clamp addresses, zero out-of-range rows (uniform predicates)
        f32x2 vc;
        {
            int t = tb - P_PAD;
            int tc = t < 0 ? 0 : (t >= T_DIM ? T_DIM - 1 : t);
            vc = xp[(size_t)tc * NC2];
            if (t < 0 || t >= T_DIM) { vc[0] = 0.f; vc[1] = 0.f; }
        }
        #pragma unroll
        for (int j = 0; j < JN - 1; ++j) {
            int t = tb - P_PAD + j + 1;
            int tc = t < 0 ? 0 : (t >= T_DIM ? T_DIM - 1 : t);
            f32x2 vn = xp[(size_t)tc * NC2];
            if (t < 0 || t >= T_DIM) { vn[0] = 0.f; vn[1] = 0.f; }
            FMAS(j, vc);
            vc = vn;
        }
        FMAS(JN - 1, vc);
    } else {
        // interior: branch-free, 2-deep pipelined loads
        f32x2 vc = xp[(size_t)(tb - P_PAD) * NC2];
        #pragma unroll
        for (int j = 0; j < JN - 1; ++j) {
            f32x2 vn = xp[(size_t)(tb - P_PAD + j + 1) * NC2];
            FMAS(j, vc);
            vc = vn;
        }
        FMAS(JN - 1, vc);
    }
#undef FMAS

    #pragma unroll
    for (int i = 0; i < TP; ++i) {
        f32x2 r; r[0] = aA[i]; r[1] = aB[i];
        op[(size_t)(tb + i) * NC2] = r;
    }
}

extern "C" void kernel_launch(void* const* d_in, const int* in_sizes, int n_in,
                              void* d_out, int out_size, void* d_ws, size_t ws_size,
                              hipStream_t stream) {
    const f32x2* x2     = (const f32x2*)d_in[0];
    const float* weight = (const float*)d_in[1];
    const float* bias   = (const float*)d_in[2];
    f32x2* out2 = (f32x2*)d_out;
    // waves = H(16) * batch-quads(8) * t-segments(128) = 16384 -> 4096 blocks
    dim3 grid(H_DIM * 8 * (T_DIM / TP) / 4);
    dim3 block(256);
    lwconv_kernel<<<grid, block, 0, stream>>>(x2, weight, bias, out2);
}

// Round 12
// 52.520 us; speedup vs baseline: 2.4871x; 1.3875x over previous
//
#include <hip/hip_runtime.h>

// LightweightConv1d: x (T,B,C) f32, weight (H,1,K) f32 (softmax over K), bias (C) f32
// out[t,b,c] = bias[c] + sum_k softmax(w[h])[k] * x[t-P+k, b, c],  h = c / (C/H)
//
// R6's exact kernel (scalar streaming accs, TT=32, VGPR=36, no spill, 52.4us)
// + NON-TEMPORAL stores. Cross-round evidence: R1/R6/R11 all pin at ~4.05 TB/s
// actual HBM throughput; dur tracks HBM bytes linearly. The input (134MB) fits
// L3 but FETCH stays ~84MB because output writes (134MB) allocate in L3 and
// evict it (268MB > 256MB). nt stores skip cache allocation -> input stays
// L3-resident -> HBM traffic ~= writes only.
#define T_DIM 2048
#define B_DIM 32
#define C_DIM 512
#define H_DIM 16
#define K_DIM 31
#define P_PAD 15
#define TT 32                      // outputs (accumulators) per thread
#define JN (TT + K_DIM - 1)        // 62 streamed inputs per thread
#define NCOL (B_DIM * C_DIM)       // 16384 floats between consecutive t

__global__ __launch_bounds__(256, 4)
void lwconv_kernel(const float* __restrict__ x, const float* __restrict__ weight,
                   const float* __restrict__ bias, float* __restrict__ out)
{
    const int wid  = __builtin_amdgcn_readfirstlane((int)(threadIdx.x >> 6));
    const int lane = threadIdx.x & 63;
    const int gw   = blockIdx.x * 4 + wid;        // global wave id (scalar)
    const int h    = gw & (H_DIM - 1);            // head (wave-uniform)
    const int bp   = (gw >> 4) & 15;              // batch pair (uniform)
    const int tblk = gw >> 8;                     // t-block 0..63 (uniform)
    const int c    = (h << 5) | (lane & 31);      // 32 channels of head h
    const int b    = (bp << 1) | (lane >> 5);     // 2 batches per wave
    const int col  = b * C_DIM + c;               // two 128B segments per wave

    // per-lane softmax of the head's 31 weights (uniform inputs), then -> SGPR
    float w[K_DIM];
    float m = -3.4e38f;
    #pragma unroll
    for (int k = 0; k < K_DIM; ++k) { w[k] = weight[h * K_DIM + k]; m = fmaxf(m, w[k]); }
    float s = 0.f;
    #pragma unroll
    for (int k = 0; k < K_DIM; ++k) { w[k] = __expf(w[k] - m); s += w[k]; }
    const float inv = 1.f / s;
    unsigned int ws[K_DIM];
    #pragma unroll
    for (int k = 0; k < K_DIM; ++k)
        ws[k] = __builtin_amdgcn_readfirstlane(__float_as_uint(w[k] * inv));

    const float bv = bias[c];
    const int tb = tblk * TT;                     // first output t of this thread
    const float* xp = x + col;
    float*       op = out + col;

    float acc[TT];
    #pragma unroll
    for (int i = 0; i < TT; ++i) acc[i] = bv;

    // Stream 62 inputs; each feeds 1..31 accumulators (partial sums -> no remat,
    // no spill at VGPR=36 proven in R6).
    #pragma unroll
    for (int j = 0; j < JN; ++j) {
        const int t  = tb - P_PAD + j;            // block-uniform
        int tc = t < 0 ? 0 : (t >= T_DIM ? T_DIM - 1 : t);
        float v = xp[(size_t)tc * NCOL];
        if (t < 0 || t >= T_DIM) v = 0.f;         // uniform cndmask/cselect
        const int ilo = (j - (K_DIM - 1)) > 0 ? (j - (K_DIM - 1)) : 0;
        const int ihi = j < (TT - 1) ? j : (TT - 1);
        #pragma unroll
        for (int i = ilo; i <= ihi; ++i)
            acc[i] = fmaf(__uint_as_float(ws[j - i]), v, acc[i]);
    }

    // Non-temporal stores: don't allocate output lines in L2/L3, so the
    // L3 keeps the input resident across replays.
    #pragma unroll
    for (int i = 0; i < TT; ++i)
        __builtin_nontemporal_store(acc[i], &op[(size_t)(tb + i) * NCOL]);
}

extern "C" void kernel_launch(void* const* d_in, const int* in_sizes, int n_in,
                              void* d_out, int out_size, void* d_ws, size_t ws_size,
                              hipStream_t stream) {
    const float* x      = (const float*)d_in[0];
    const float* weight = (const float*)d_in[1];
    const float* bias   = (const float*)d_in[2];
    float* out = (float*)d_out;
    // waves = H(16) * batch-pairs(16) * t-blocks(64) = 16384 -> 4096 blocks of 4 waves
    dim3 grid(H_DIM * 16 * (T_DIM / TT) / 4);
    dim3 block(256);
    lwconv_kernel<<<grid, block, 0, stream>>>(x, weight, bias, out);
}

// Round 13
// 50.403 us; speedup vs baseline: 2.5916x; 1.0420x over previous
//
#include <hip/hip_runtime.h>

// LightweightConv1d: x (T,B,C) f32, weight (H,1,K) f32 (softmax over K), bias (C) f32
// out[t,b,c] = bias[c] + sum_k softmax(w[h])[k] * x[t-P+k, b, c],  h = c / (C/H)
//
// R6/R12 skeleton (scalar streaming accs, TT=32, proven no-spill) + RAW-ASM
// pipelined loads. R12 proved we're latency-bound (nt stores cut FETCH 17%,
// dur unchanged): compiler keeps 1 load in flight (load->waitcnt->31FMA->...).
// Fix at ISA level: inline-asm global_load_dword (opaque to the allocator: no
// remat, no reorder) issued in double-buffered batches of 16 with hand-placed
// s_waitcnt vmcnt(16) (never 0 until drain) -> 16-32 loads in flight per wave.
// The waitcnt asm carries the batch as "+v" operands: FMAs are data-dependent
// on the post-wait values -> cannot hoist above it (rule #18 via dataflow).
#define T_DIM 2048
#define B_DIM 32
#define C_DIM 512
#define H_DIM 16
#define K_DIM 31
#define P_PAD 15
#define TT 32                      // outputs (accumulators) per thread
#define NCOL (B_DIM * C_DIM)       // 16384 floats between consecutive t
#define TSTEP 65536u               // NCOL*4 bytes: byte stride between t-rows

__global__ __launch_bounds__(256, 4)
void lwconv_kernel(const float* __restrict__ x, const float* __restrict__ weight,
                   const float* __restrict__ bias, float* __restrict__ out)
{
    const int wid  = __builtin_amdgcn_readfirstlane((int)(threadIdx.x >> 6));
    const int lane = threadIdx.x & 63;
    const int gw   = blockIdx.x * 4 + wid;        // global wave id (scalar)
    const int h    = gw & (H_DIM - 1);            // head (wave-uniform)
    const int bp   = (gw >> 4) & 15;              // batch pair (uniform)
    const int tblk = gw >> 8;                     // t-block 0..63 (uniform)
    const int c    = (h << 5) | (lane & 31);      // 32 channels of head h
    const int b    = (bp << 1) | (lane >> 5);     // 2 batches per wave
    const int col  = b * C_DIM + c;               // two 128B segments per wave

    // per-lane softmax of the head's 31 weights (uniform inputs), then -> SGPR
    float w[K_DIM];
    float m = -3.4e38f;
    #pragma unroll
    for (int k = 0; k < K_DIM; ++k) { w[k] = weight[h * K_DIM + k]; m = fmaxf(m, w[k]); }
    float s = 0.f;
    #pragma unroll
    for (int k = 0; k < K_DIM; ++k) { w[k] = __expf(w[k] - m); s += w[k]; }
    const float inv = 1.f / s;
    unsigned int ws[K_DIM];
    #pragma unroll
    for (int k = 0; k < K_DIM; ++k)
        ws[k] = __builtin_amdgcn_readfirstlane(__float_as_uint(w[k] * inv));

    const float bv = bias[c];
    const int tb = tblk * TT;                     // first output t of this thread
    float* op = out + col;

    float acc[TT];
    #pragma unroll
    for (int i = 0; i < TT; ++i) acc[i] = bv;

#define FMAS(J, V)                                                        \
    {                                                                     \
        const int ilo = ((J) - (K_DIM - 1)) > 0 ? ((J) - (K_DIM - 1)) : 0;\
        const int ihi = (J) < (TT - 1) ? (J) : (TT - 1);                  \
        _Pragma("unroll")                                                 \
        for (int i = ilo; i <= ihi; ++i)                                  \
            acc[i] = fmaf(__uint_as_float(ws[(J) - i]), (V), acc[i]);     \
    }

    if (tblk == 0 || tblk == (T_DIM / TT) - 1) {
        // boundary t-blocks (2 of 64): serial clamped path (R12-proven)
        const float* xp = x + col;
        #pragma unroll
        for (int j = 0; j < TT + K_DIM - 1; ++j) {
            const int t  = tb - P_PAD + j;
            int tc = t < 0 ? 0 : (t >= T_DIM ? T_DIM - 1 : t);
            float v = xp[(size_t)tc * NCOL];
            if (t < 0 || t >= T_DIM) v = 0.f;
            FMAS(j, v);
        }
    } else {
        // interior: rows tb-15 .. tb+48 all in-range (tblk 1..62); load 64 rows
        // (j=62,63 are dead: FMAS range empty) in 4 batches of 16, 2-deep dbuf.
        const unsigned long long xb = (unsigned long long)(const void*)x;
        unsigned int voff = ((unsigned)col << 2) + (unsigned)(tb - P_PAD) * TSTEP;
        float A[16], Bv[16];

#define ISSUE16(BUF)                                                      \
        _Pragma("unroll")                                                 \
        for (int u = 0; u < 16; ++u) {                                    \
            asm volatile("global_load_dword %0, %1, %2"                   \
                         : "=v"(BUF[u]) : "v"(voff), "s"(xb));            \
            voff += TSTEP;                                                \
        }

#define WAITB(N, BUF)                                                     \
        asm volatile("s_waitcnt vmcnt(" #N ")"                            \
                : "+v"(BUF[0]), "+v"(BUF[1]), "+v"(BUF[2]),  "+v"(BUF[3]),\
                  "+v"(BUF[4]), "+v"(BUF[5]), "+v"(BUF[6]),  "+v"(BUF[7]),\
                  "+v"(BUF[8]), "+v"(BUF[9]), "+v"(BUF[10]), "+v"(BUF[11]),\
                  "+v"(BUF[12]),"+v"(BUF[13]),"+v"(BUF[14]), "+v"(BUF[15]));

#define FMA16(BASE, BUF)                                                  \
        _Pragma("unroll")                                                 \
        for (int u = 0; u < 16; ++u) { FMAS((BASE) + u, BUF[u]); }

        ISSUE16(A);           // j 0-15   (16 in flight)
        ISSUE16(Bv);          // j 16-31  (32 in flight)
        WAITB(16, A);         // A landed; Bv still flying
        FMA16(0, A);
        ISSUE16(A);           // j 32-47  (32 in flight)
        WAITB(16, Bv);
        FMA16(16, Bv);
        ISSUE16(Bv);          // j 48-63  (32 in flight)
        WAITB(16, A);
        FMA16(32, A);
        WAITB(0, Bv);
        FMA16(48, Bv);        // j 62,63 produce no FMAs (empty range)

#undef ISSUE16
#undef WAITB
#undef FMA16
    }
#undef FMAS

    // nt stores: keep output lines out of L3 so the input stays resident (R12)
    #pragma unroll
    for (int i = 0; i < TT; ++i)
        __builtin_nontemporal_store(acc[i], &op[(size_t)(tb + i) * NCOL]);
}

extern "C" void kernel_launch(void* const* d_in, const int* in_sizes, int n_in,
                              void* d_out, int out_size, void* d_ws, size_t ws_size,
                              hipStream_t stream) {
    const float* x      = (const float*)d_in[0];
    const float* weight = (const float*)d_in[1];
    const float* bias   = (const float*)d_in[2];
    float* out = (float*)d_out;
    // waves = H(16) * batch-pairs(16) * t-blocks(64) = 16384 -> 4096 blocks of 4 waves
    dim3 grid(H_DIM * 16 * (T_DIM / TT) / 4);
    dim3 block(256);
    lwconv_kernel<<<grid, block, 0, stream>>>(x, weight, bias, out);
}